// Round 1
// baseline (250.422 us; speedup 1.0000x reference)
//
#include <hip/hip_runtime.h>

// HierarchicalClassifier: B=16384, D=2048, N_TOP=8, N_CLASS=16
// out[b, t*16+c] = sigmoid(f.top_W[t]+top_b[t]) * softmax_c(f.bottom_W[t,:,c]+bottom_b[t,c])
//
// Strategy: single fused fp16-MFMA skinny GEMM (N=144 incl. 8 pad cols),
// memory-bound on the 134 MB feature read. K split 4-ways across the
// workgroup's waves; LDS reduction + softmax epilogue in the same kernel.

#define D_DIM 2048
#define NTILE 9          // 144 columns / 16
#define NCOLS 144

using f32x4 = float __attribute__((ext_vector_type(4)));
using half8 = _Float16 __attribute__((ext_vector_type(8)));

// Pack [top_W (8,2048); bottom_W (8,2048,16) -> (t,c) cols; 8 zero cols]
// into W[n][k] fp16, n in [0,144), k-contiguous (MFMA B-fragment friendly).
__global__ void prep_weights(const float* __restrict__ topW,
                             const float* __restrict__ botW,
                             _Float16* __restrict__ W) {
    int idx = blockIdx.x * blockDim.x + threadIdx.x;   // over 144*2048
    if (idx >= NCOLS * D_DIM) return;
    int n = idx >> 11;            // / 2048
    int k = idx & (D_DIM - 1);
    float v = 0.0f;
    if (n < 8) {
        v = topW[n * D_DIM + k];
    } else if (n < 136) {
        int t = (n - 8) >> 4, c = (n - 8) & 15;
        v = botW[(t * D_DIM + k) * 16 + c];
    }
    W[idx] = (_Float16)v;          // RNE
}

__global__ __launch_bounds__(256, 4) void hc_fused(
        const float* __restrict__ feat, const _Float16* __restrict__ W,
        const float* __restrict__ top_b, const float* __restrict__ bot_b,
        float* __restrict__ out) {
    __shared__ float red[4][16][148];   // [wave][row][ncol(+pad)]

    const int tid  = threadIdx.x;
    const int lane = tid & 63, wave = tid >> 6;
    const int quad = lane >> 4, low = lane & 15;
    const size_t row0 = (size_t)blockIdx.x * 16;

    // A: lane holds A[m=low][k = quad*8 + j], j=0..7, within each 32-k step.
    // This wave covers K range [wave*512, wave*512+512).
    const f32x4* Ap = (const f32x4*)(feat + (row0 + low) * D_DIM + wave * 512 + quad * 8);
    // B: lane holds B[n = low][k = quad*8 + j]; per n-tile add nt*16 rows.
    const _Float16* Bbase = W + (size_t)low * D_DIM + wave * 512 + quad * 8;

    f32x4 acc[NTILE];
    #pragma unroll
    for (int i = 0; i < NTILE; i++) acc[i] = (f32x4)0.0f;

    #pragma unroll 2
    for (int ks = 0; ks < 16; ks++) {           // 16 steps of K=32
        f32x4 a0 = Ap[ks * 8];
        f32x4 a1 = Ap[ks * 8 + 1];
        half8 af;
        af[0] = (_Float16)a0[0]; af[1] = (_Float16)a0[1];
        af[2] = (_Float16)a0[2]; af[3] = (_Float16)a0[3];
        af[4] = (_Float16)a1[0]; af[5] = (_Float16)a1[1];
        af[6] = (_Float16)a1[2]; af[7] = (_Float16)a1[3];
        #pragma unroll
        for (int nt = 0; nt < NTILE; nt++) {
            half8 bf = *(const half8*)(Bbase + nt * 16 * D_DIM + ks * 32);
            acc[nt] = __builtin_amdgcn_mfma_f32_16x16x32_f16(af, bf, acc[nt], 0, 0, 0);
        }
    }

    // C/D layout (measured m89/m91): col = lane&15, row = quad*4 + reg.
    #pragma unroll
    for (int nt = 0; nt < NTILE; nt++) {
        #pragma unroll
        for (int r = 0; r < 4; r++) {
            red[wave][quad * 4 + r][nt * 16 + low] = acc[nt][r];
        }
    }
    __syncthreads();

    // Epilogue: thread (row = tid>>4, top = tid&15 when <8) handles one
    // (row, top) pair: sigmoid gate * softmax over its 16 classes.
    const int row = tid >> 4;
    const int top = tid & 15;
    if (top < 8) {
        float zt = top_b[top];
        #pragma unroll
        for (int w = 0; w < 4; w++) zt += red[w][row][top];
        const float sig = 1.0f / (1.0f + __expf(-zt));

        float z[16];
        float zmax = -1e30f;
        #pragma unroll
        for (int c = 0; c < 16; c++) {
            float v = bot_b[top * 16 + c];
            #pragma unroll
            for (int w = 0; w < 4; w++) v += red[w][row][8 + top * 16 + c];
            z[c] = v;
            zmax = fmaxf(zmax, v);
        }
        float s = 0.0f;
        #pragma unroll
        for (int c = 0; c < 16; c++) { z[c] = __expf(z[c] - zmax); s += z[c]; }
        const float scale = sig / s;

        float* o = out + (row0 + row) * 128 + top * 16;
        #pragma unroll
        for (int c = 0; c < 16; c += 4) {
            f32x4 v = { z[c] * scale, z[c+1] * scale, z[c+2] * scale, z[c+3] * scale };
            *(f32x4*)(o + c) = v;
        }
    }
}

extern "C" void kernel_launch(void* const* d_in, const int* in_sizes, int n_in,
                              void* d_out, int out_size, void* d_ws, size_t ws_size,
                              hipStream_t stream) {
    const float* feat  = (const float*)d_in[0];   // (16384, 2048)
    const float* topW  = (const float*)d_in[1];   // (8, 2048)
    const float* topB  = (const float*)d_in[2];   // (8,)
    const float* botW  = (const float*)d_in[3];   // (8, 2048, 16)
    const float* botB  = (const float*)d_in[4];   // (8, 16)
    float* out = (float*)d_out;                   // (16384, 128)
    _Float16* W = (_Float16*)d_ws;                // 144*2048 fp16 = 576 KB

    prep_weights<<<(NCOLS * D_DIM + 255) / 256, 256, 0, stream>>>(topW, botW, W);
    hc_fused<<<16384 / 16, 256, 0, stream>>>(feat, W, topB, botB, out);
}

// Round 2
// 214.827 us; speedup vs baseline: 1.1657x; 1.1657x over previous
//
#include <hip/hip_runtime.h>

// HierarchicalClassifier: B=16384, D=2048, N_TOP=8, N_CLASS=16
// out[b, t*16+c] = sigmoid(f.top_W[t]+top_b[t]) * softmax_c(f.bottom_W[t,:,c]+bottom_b[t,c])
//
// R2: B weights pre-swizzled into exact MFMA-fragment order so every B load
// is a fully-coalesced contiguous 1 KB wave read (R1 had 4KB-stride lane
// pattern -> 2x cache-line transactions + scattered L2 stream; txn-bound at
// 108us with all pipes <4% busy).

#define D_DIM 2048
#define NTILE 9          // 144 columns / 16
#define NCOLS 144

using f32x4 = float __attribute__((ext_vector_type(4)));
using half8 = _Float16 __attribute__((ext_vector_type(8)));

// Swizzled B layout: S[(((w*16 + ks)*9 + nt)*64 + lane)*8 + j]
//   = W[n = nt*16 + (lane&15)][k = w*512 + ks*32 + (lane>>4)*8 + j]
// where W rows 0..7 = top_W, 8..135 = bottom_W[t][:,c] (n-8 = t*16+c), 136..143 = 0.
// One thread per (w,ks,nt,lane): writes 8 contiguous halfs (16B, coalesced).
__global__ void prep_weights(const float* __restrict__ topW,
                             const float* __restrict__ botW,
                             _Float16* __restrict__ S) {
    int idx = blockIdx.x * blockDim.x + threadIdx.x;   // [0, 4*16*9*64)
    if (idx >= 4 * 16 * NTILE * 64) return;
    int lane = idx & 63;
    int tmp  = idx >> 6;          // (w*16+ks)*9 + nt
    int nt   = tmp % NTILE;
    int wks  = tmp / NTILE;       // w*16+ks in [0,64)
    int n     = nt * 16 + (lane & 15);
    int kbase = wks * 32 + (lane >> 4) * 8;

    _Float16 v[8];
    #pragma unroll
    for (int j = 0; j < 8; j++) {
        int k = kbase + j;
        float x = 0.0f;
        if (n < 8) {
            x = topW[n * D_DIM + k];
        } else if (n < 136) {
            int t = (n - 8) >> 4, c = (n - 8) & 15;
            x = botW[(t * D_DIM + k) * 16 + c];
        }
        v[j] = (_Float16)x;
    }
    *(half8*)(S + (size_t)idx * 8) = *(half8*)v;
}

__global__ __launch_bounds__(256, 4) void hc_fused(
        const float* __restrict__ feat, const _Float16* __restrict__ Bsw,
        const float* __restrict__ top_b, const float* __restrict__ bot_b,
        float* __restrict__ out) {
    __shared__ float red[4][16][148];   // [wave][row][ncol(+pad)]

    const int tid  = threadIdx.x;
    const int lane = tid & 63, wave = tid >> 6;
    const int quad = lane >> 4, low = lane & 15;
    const size_t row0 = (size_t)blockIdx.x * 16;

    // A: lane holds A[m=low][k = quad*8 + j]; this wave's K range = [wave*512, +512)
    const f32x4* Ap = (const f32x4*)(feat + (row0 + low) * D_DIM + wave * 512 + quad * 8);
    // B: swizzled fragment stream; per (ks,nt) a contiguous 1KB wave read.
    const _Float16* Bw = Bsw + (size_t)wave * (16 * NTILE * 512) + lane * 8;

    f32x4 acc[NTILE];
    #pragma unroll
    for (int i = 0; i < NTILE; i++) acc[i] = (f32x4)0.0f;

    #pragma unroll 4
    for (int ks = 0; ks < 16; ks++) {           // 16 steps of K=32
        f32x4 a0 = Ap[ks * 8];
        f32x4 a1 = Ap[ks * 8 + 1];
        half8 bf[NTILE];
        #pragma unroll
        for (int nt = 0; nt < NTILE; nt++)
            bf[nt] = *(const half8*)(Bw + (ks * NTILE + nt) * 512);
        half8 af;
        af[0] = (_Float16)a0[0]; af[1] = (_Float16)a0[1];
        af[2] = (_Float16)a0[2]; af[3] = (_Float16)a0[3];
        af[4] = (_Float16)a1[0]; af[5] = (_Float16)a1[1];
        af[6] = (_Float16)a1[2]; af[7] = (_Float16)a1[3];
        #pragma unroll
        for (int nt = 0; nt < NTILE; nt++)
            acc[nt] = __builtin_amdgcn_mfma_f32_16x16x32_f16(af, bf[nt], acc[nt], 0, 0, 0);
    }

    // C/D layout (measured m89/m91): col = lane&15, row = quad*4 + reg.
    #pragma unroll
    for (int nt = 0; nt < NTILE; nt++) {
        #pragma unroll
        for (int r = 0; r < 4; r++) {
            red[wave][quad * 4 + r][nt * 16 + low] = acc[nt][r];
        }
    }
    __syncthreads();

    // Epilogue: thread (row = tid>>4, top = tid&15 when <8) handles one
    // (row, top) pair: sigmoid gate * softmax over its 16 classes.
    const int row = tid >> 4;
    const int top = tid & 15;
    if (top < 8) {
        float zt = top_b[top];
        #pragma unroll
        for (int w = 0; w < 4; w++) zt += red[w][row][top];
        const float sig = 1.0f / (1.0f + __expf(-zt));

        float z[16];
        float zmax = -1e30f;
        #pragma unroll
        for (int c = 0; c < 16; c++) {
            float v = bot_b[top * 16 + c];
            #pragma unroll
            for (int w = 0; w < 4; w++) v += red[w][row][8 + top * 16 + c];
            z[c] = v;
            zmax = fmaxf(zmax, v);
        }
        float s = 0.0f;
        #pragma unroll
        for (int c = 0; c < 16; c++) { z[c] = __expf(z[c] - zmax); s += z[c]; }
        const float scale = sig / s;

        float* o = out + (row0 + row) * 128 + top * 16;
        #pragma unroll
        for (int c = 0; c < 16; c += 4) {
            f32x4 v = { z[c] * scale, z[c+1] * scale, z[c+2] * scale, z[c+3] * scale };
            *(f32x4*)(o + c) = v;
        }
    }
}

extern "C" void kernel_launch(void* const* d_in, const int* in_sizes, int n_in,
                              void* d_out, int out_size, void* d_ws, size_t ws_size,
                              hipStream_t stream) {
    const float* feat  = (const float*)d_in[0];   // (16384, 2048)
    const float* topW  = (const float*)d_in[1];   // (8, 2048)
    const float* topB  = (const float*)d_in[2];   // (8,)
    const float* botW  = (const float*)d_in[3];   // (8, 2048, 16)
    const float* botB  = (const float*)d_in[4];   // (8, 16)
    float* out = (float*)d_out;                   // (16384, 128)
    _Float16* Bsw = (_Float16*)d_ws;              // 144*2048 fp16 = 576 KB swizzled

    prep_weights<<<(4 * 16 * NTILE * 64 + 255) / 256, 256, 0, stream>>>(topW, botW, Bsw);
    hc_fused<<<16384 / 16, 256, 0, stream>>>(feat, Bsw, topB, botB, out);
}

// Round 3
// 209.547 us; speedup vs baseline: 1.1951x; 1.0252x over previous
//
#include <hip/hip_runtime.h>

// HierarchicalClassifier: B=16384, D=2048, N_TOP=8, N_CLASS=16
// out[b, t*16+c] = sigmoid(f.top_W[t]+top_b[t]) * softmax_c(f.bottom_W[t,:,c]+bottom_b[t,c])
//
// R3: M=32 rows/WG (B-frag reuse x2 -> L2 B traffic halves, 2x per-wave ILP)
// + __launch_bounds__(256,2) to open the VGPR budget (R2's VGPR=60 forced a
// serialized load->mfma chain with exposed L2 latency).

#define D_DIM 2048
#define NTILE 9          // 144 columns / 16
#define NCOLS 144
#define M_ROWS 32        // rows per workgroup (2 row-tiles of 16)

using f32x4 = float __attribute__((ext_vector_type(4)));
using half8 = _Float16 __attribute__((ext_vector_type(8)));

// Swizzled B layout: S[(((w*16 + ks)*9 + nt)*64 + lane)*8 + j]
//   = W[n = nt*16 + (lane&15)][k = w*512 + ks*32 + (lane>>4)*8 + j]
// W rows 0..7 = top_W, 8..135 = bottom_W[t][:,c] (n-8 = t*16+c), 136..143 = 0.
__global__ void prep_weights(const float* __restrict__ topW,
                             const float* __restrict__ botW,
                             _Float16* __restrict__ S) {
    int idx = blockIdx.x * blockDim.x + threadIdx.x;   // [0, 4*16*9*64)
    if (idx >= 4 * 16 * NTILE * 64) return;
    int lane = idx & 63;
    int tmp  = idx >> 6;          // (w*16+ks)*9 + nt
    int nt   = tmp % NTILE;
    int wks  = tmp / NTILE;       // w*16+ks in [0,64)
    int n     = nt * 16 + (lane & 15);
    int kbase = wks * 32 + (lane >> 4) * 8;

    _Float16 v[8];
    #pragma unroll
    for (int j = 0; j < 8; j++) {
        int k = kbase + j;
        float x = 0.0f;
        if (n < 8) {
            x = topW[n * D_DIM + k];
        } else if (n < 136) {
            int t = (n - 8) >> 4, c = (n - 8) & 15;
            x = botW[(t * D_DIM + k) * 16 + c];
        }
        v[j] = (_Float16)x;
    }
    *(half8*)(S + (size_t)idx * 8) = *(half8*)v;
}

__global__ __launch_bounds__(256, 2) void hc_fused(
        const float* __restrict__ feat, const _Float16* __restrict__ Bsw,
        const float* __restrict__ top_b, const float* __restrict__ bot_b,
        float* __restrict__ out) {
    __shared__ float red[4][M_ROWS][148];   // [wave][row][ncol(+pad)] = 74 KB

    const int tid  = threadIdx.x;
    const int lane = tid & 63, wave = tid >> 6;
    const int quad = lane >> 4, low = lane & 15;
    const size_t row0 = (size_t)blockIdx.x * M_ROWS;

    // A: lane holds A[m=low][k = quad*8 + j]; this wave's K range = [wave*512, +512)
    const f32x4* Ap0 = (const f32x4*)(feat + (row0 + low) * D_DIM + wave * 512 + quad * 8);
    const f32x4* Ap1 = (const f32x4*)(feat + (row0 + 16 + low) * D_DIM + wave * 512 + quad * 8);
    // B: swizzled fragment stream; per (ks,nt) a contiguous 1KB wave read.
    const _Float16* Bw = Bsw + (size_t)wave * (16 * NTILE * 512) + lane * 8;

    f32x4 acc0[NTILE], acc1[NTILE];
    #pragma unroll
    for (int i = 0; i < NTILE; i++) { acc0[i] = (f32x4)0.0f; acc1[i] = (f32x4)0.0f; }

    #pragma unroll 2
    for (int ks = 0; ks < 16; ks++) {           // 16 steps of K=32
        f32x4 a00 = Ap0[ks * 8];
        f32x4 a01 = Ap0[ks * 8 + 1];
        f32x4 a10 = Ap1[ks * 8];
        f32x4 a11 = Ap1[ks * 8 + 1];
        half8 bf[NTILE];
        #pragma unroll
        for (int nt = 0; nt < NTILE; nt++)
            bf[nt] = *(const half8*)(Bw + (ks * NTILE + nt) * 512);
        half8 af0, af1;
        af0[0] = (_Float16)a00[0]; af0[1] = (_Float16)a00[1];
        af0[2] = (_Float16)a00[2]; af0[3] = (_Float16)a00[3];
        af0[4] = (_Float16)a01[0]; af0[5] = (_Float16)a01[1];
        af0[6] = (_Float16)a01[2]; af0[7] = (_Float16)a01[3];
        af1[0] = (_Float16)a10[0]; af1[1] = (_Float16)a10[1];
        af1[2] = (_Float16)a10[2]; af1[3] = (_Float16)a10[3];
        af1[4] = (_Float16)a11[0]; af1[5] = (_Float16)a11[1];
        af1[6] = (_Float16)a11[2]; af1[7] = (_Float16)a11[3];
        #pragma unroll
        for (int nt = 0; nt < NTILE; nt++) {
            acc0[nt] = __builtin_amdgcn_mfma_f32_16x16x32_f16(af0, bf[nt], acc0[nt], 0, 0, 0);
            acc1[nt] = __builtin_amdgcn_mfma_f32_16x16x32_f16(af1, bf[nt], acc1[nt], 0, 0, 0);
        }
    }

    // C/D layout (measured m89/m91): col = lane&15, row = quad*4 + reg.
    #pragma unroll
    for (int nt = 0; nt < NTILE; nt++) {
        #pragma unroll
        for (int r = 0; r < 4; r++) {
            red[wave][quad * 4 + r][nt * 16 + low]      = acc0[nt][r];
            red[wave][16 + quad * 4 + r][nt * 16 + low] = acc1[nt][r];
        }
    }
    __syncthreads();

    // Epilogue: thread -> (row = tid>>3 in [0,32), top = tid&7). All active.
    const int row = tid >> 3;
    const int top = tid & 7;
    {
        float zt = top_b[top];
        #pragma unroll
        for (int w = 0; w < 4; w++) zt += red[w][row][top];
        const float sig = 1.0f / (1.0f + __expf(-zt));

        float z[16];
        float zmax = -1e30f;
        #pragma unroll
        for (int c = 0; c < 16; c++) {
            float v = bot_b[top * 16 + c];
            #pragma unroll
            for (int w = 0; w < 4; w++) v += red[w][row][8 + top * 16 + c];
            z[c] = v;
            zmax = fmaxf(zmax, v);
        }
        float s = 0.0f;
        #pragma unroll
        for (int c = 0; c < 16; c++) { z[c] = __expf(z[c] - zmax); s += z[c]; }
        const float scale = sig / s;

        float* o = out + (row0 + row) * 128 + top * 16;
        #pragma unroll
        for (int c = 0; c < 16; c += 4) {
            f32x4 v = { z[c] * scale, z[c+1] * scale, z[c+2] * scale, z[c+3] * scale };
            *(f32x4*)(o + c) = v;
        }
    }
}

extern "C" void kernel_launch(void* const* d_in, const int* in_sizes, int n_in,
                              void* d_out, int out_size, void* d_ws, size_t ws_size,
                              hipStream_t stream) {
    const float* feat  = (const float*)d_in[0];   // (16384, 2048)
    const float* topW  = (const float*)d_in[1];   // (8, 2048)
    const float* topB  = (const float*)d_in[2];   // (8,)
    const float* botW  = (const float*)d_in[3];   // (8, 2048, 16)
    const float* botB  = (const float*)d_in[4];   // (8, 16)
    float* out = (float*)d_out;                   // (16384, 128)
    _Float16* Bsw = (_Float16*)d_ws;              // 144*2048 fp16 = 576 KB swizzled

    prep_weights<<<(4 * 16 * NTILE * 64 + 255) / 256, 256, 0, stream>>>(topW, botW, Bsw);
    hc_fused<<<16384 / M_ROWS, 256, 0, stream>>>(feat, Bsw, topB, botB, out);
}